// Round 5
// baseline (12.727 us; speedup 1.0000x reference)
//
#include <hip/hip_runtime.h>
#include <math.h>

#define NLOC 21504
#define N3 16384
#define N4 4096
#define N5 1024
#define CHUNKS 42   // 42 chunks of 512 locations per batch, 2 locations/thread
// p3: chunks 0..31  (4 rows x 128), wave covers rows {r, r+2} in one 64-col half
// p4: chunks 32..39 (8 rows x 64),  wave covers rows {r, r+4}, full width
// p5: chunks 40..41 (16 rows x 32), wave covers rows {r,r+1,r+8,r+9}, full width

__global__ __launch_bounds__(256) void fcos_assign(
    const float* __restrict__ gt,      // (16, 64, 5)
    const float* __restrict__ pred3,   // (16, 16384, 4)
    const float* __restrict__ pred4,   // (16, 4096, 4)
    const float* __restrict__ pred5,   // (16, 1024, 4)
    float* __restrict__ out)           // (16, 21504, 14)
{
    // Wave-private everything: NO __syncthreads in the kernel.
    __shared__ float scand[4][64][8];     // 8 KiB  [x0,y0,x1,y1,cls,q,-,-]
    __shared__ float sout[2][4][896];     // 28 KiB (2 store passes, dbuf)

    const int tid   = threadIdx.x;
    const int lane  = tid & 63;
    const int w     = tid >> 6;
    const int b     = blockIdx.x / CHUNKS;
    const int chunk = blockIdx.x % CHUNKS;

    // ---- two locations per thread: i0 and i0+256 (same level, same column) ----
    const int i0 = chunk * 512 + tid;
    float cx, cy0, cy1, stride, inv_stride, lower, upper;
    float cx_min, cx_max, cy_min, cy_max;     // wave window (covers both k)
    const float4 *pp0, *pp1;
    if (chunk < 32) {                         // p3
        const int row0 = chunk * 4 + (w >> 1);
        const int c0   = (w & 1) * 64;
        const int col  = c0 + lane;
        cx  = (col + 0.5f) * 8.0f;
        cy0 = (row0 + 0.5f) * 8.0f;
        cy1 = (row0 + 2.5f) * 8.0f;           // +2 rows
        stride = 8.0f; inv_stride = 0.125f; lower = 0.0f; upper = 64.0f;
        cy_min = cy0; cy_max = cy1;
        cx_min = (c0 + 0.5f) * 8.0f;  cx_max = (c0 + 63.5f) * 8.0f;
        pp0 = (const float4*)(pred3 + ((size_t)b * N3 + i0) * 4);
    } else if (chunk < 40) {                  // p4
        const int il0  = i0 - N3;
        const int row0 = (chunk - 32) * 8 + w;
        cx  = (lane + 0.5f) * 16.0f;
        cy0 = (row0 + 0.5f) * 16.0f;
        cy1 = (row0 + 4.5f) * 16.0f;          // +4 rows
        stride = 16.0f; inv_stride = 0.0625f; lower = 64.0f; upper = 128.0f;
        cy_min = cy0; cy_max = cy1;
        cx_min = 8.0f; cx_max = 1016.0f;
        pp0 = (const float4*)(pred4 + ((size_t)b * N4 + il0) * 4);
    } else {                                  // p5
        const int il0  = i0 - N3 - N4;
        const int row0 = il0 >> 5;
        const int rb   = (chunk - 40) * 16 + w * 2;
        cx  = ((lane & 31) + 0.5f) * 32.0f;
        cy0 = (row0 + 0.5f) * 32.0f;
        cy1 = (row0 + 8.5f) * 32.0f;          // +8 rows
        stride = 32.0f; inv_stride = 0.03125f; lower = 128.0f; upper = INFINITY;
        cy_min = (rb + 0.5f) * 32.0f; cy_max = (rb + 9.5f) * 32.0f;
        cx_min = 16.0f; cx_max = 1008.0f;
        pp0 = (const float4*)(pred5 + ((size_t)b * N5 + il0) * 4);
    }
    pp1 = pp0 + 256;   // +256 locations

    // ---- prefetch both predictions (latency hides under filter/loop) ----
    const float4 p0 = *pp0;
    const float4 p1 = *pp1;

    // ---- per-wave candidate filter: lane <-> box, ballot-compact ----
    // Necessary conditions only, 0.25px margin >> any f32 rounding of the
    // reference's per-location tests => never drops a matchable box.
    // Order-preserving compaction keeps jnp.argmax first-max-wins semantics.
    const float* g = gt + (size_t)b * 320 + lane * 5;
    const float bx0 = g[0], by0 = g[1], bx1 = g[2], by1 = g[3], bcl = g[4];
    const float eps = 0.25f;
    const float ylo = fmaxf(by0, by1 - upper), yhi = fminf(by1, by0 + upper);
    const float xlo = fmaxf(bx0, bx1 - upper), xhi = fminf(bx1, bx0 + upper);
    const bool keep = (ylo < cy_max + eps) && (yhi > cy_min - eps)
                   && (xlo < cx_max + eps) && (xhi > cx_min - eps)
                   && (fmaxf(bx1 - bx0, by1 - by0) > lower - eps);
    const unsigned long long mball = __ballot(keep);
    const int cnt = (int)__popcll(mball);
    if (keep) {
        const int pos = (int)__popcll(mball & ((1ull << lane) - 1ull));
        scand[w][pos][0] = bx0; scand[w][pos][1] = by0;
        scand[w][pos][2] = bx1; scand[w][pos][3] = by1;
        scand[w][pos][4] = bcl;
        // Exactly match JAX: q = 1e8 - (x1-x0)*(y1-y0), no FMA contraction.
        scand[w][pos][5] = __fsub_rn(1.0e8f,
                            __fmul_rn(__fsub_rn(bx1, bx0), __fsub_rn(by1, by0)));
    }
    __builtin_amdgcn_wave_barrier();   // wave-synchronous LDS write->read order

    // ---- match loop: one candidate load serves BOTH locations (same cx) ----
    float best0 = 0.0f, best1 = 0.0f;
    int   bi0   = -1,   bi1   = -1;
    for (int j = 0; j < cnt; ++j) {
        const float4 bx = *(const float4*)&scand[w][j][0];  // broadcast b128
        const float  q  = scand[w][j][5];
        const float dl = cx - bx.x;          // shared: same column
        const float dr = bx.z - cx;
        const float hx_mn = fminf(dl, dr), hx_mx = fmaxf(dl, dr);
        // location 0
        const float dt0 = cy0 - bx.y, db0 = bx.w - cy0;
        const float mn0 = fminf(hx_mn, fminf(dt0, db0));
        const float mx0 = fmaxf(hx_mx, fmaxf(dt0, db0));
        const bool u0 = (mn0 > 0.0f) && (mx0 > lower) && (mx0 < upper) && (q > best0);
        best0 = u0 ? q : best0;  bi0 = u0 ? j : bi0;
        // location 1
        const float dt1 = cy1 - bx.y, db1 = bx.w - cy1;
        const float mn1 = fminf(hx_mn, fminf(dt1, db1));
        const float mx1 = fmaxf(hx_mx, fmaxf(dt1, db1));
        const bool u1 = (mn1 > 0.0f) && (mx1 > lower) && (mx1 < upper) && (q > best1);
        best1 = u1 ? q : best1;  bi1 = u1 ? j : bi1;
    }

    // ---- epilogue per location, staged to wave-private LDS ----
    #pragma unroll
    for (int k = 0; k < 2; ++k) {
        const int bi = k ? bi1 : bi0;
        const float cy = k ? cy1 : cy0;
        const float4 p = k ? p1 : p0;
        float m0, m1, m2, m3, m4;
        if (bi < 0) {
            m0 = m1 = m2 = m3 = m4 = -1.0f;
        } else {
            const float4 bb = *(const float4*)&scand[w][bi][0];
            m0 = bb.x; m1 = bb.y; m2 = bb.z; m3 = bb.w;
            m4 = scand[w][bi][4];
        }
        float t0, t1, t2, t3, ctr;
        if (m4 == -1.0f) {
            t0 = t1 = t2 = t3 = -1.0f; ctr = -1.0f;
        } else {
            t0 = (cx - m0) * inv_stride;   // exact: stride = 2^k
            t1 = (cy - m1) * inv_stride;
            t2 = (m2 - cx) * inv_stride;
            t3 = (m3 - cy) * inv_stride;
            const float num = fminf(t0, t2) * fminf(t1, t3);
            const float den = fmaxf(t0, t2) * fmaxf(t1, t3);
            ctr = sqrtf(num / den);
        }
        const float d0 = cx - fmaxf(p.x, 0.0f) * stride;
        const float d1 = cy - fmaxf(p.y, 0.0f) * stride;
        const float d2 = cx + fmaxf(p.z, 0.0f) * stride;
        const float d3 = cy + fmaxf(p.w, 0.0f) * stride;

        float2* so2 = (float2*)&sout[k][w][lane * 14];
        so2[0] = make_float2(d0, d1);
        so2[1] = make_float2(d2, d3);
        so2[2] = make_float2(m0, m1);
        so2[3] = make_float2(m2, m3);
        so2[4] = make_float2(m4, t0);
        so2[5] = make_float2(t1, t2);
        so2[6] = make_float2(t3, ctr);
    }
    __builtin_amdgcn_wave_barrier();

    // ---- coalesced float4 stores: 224 per wave per pass, contiguous ----
    #pragma unroll
    for (int k = 0; k < 2; ++k) {
        float4* ob = (float4*)(out +
            (((size_t)b * NLOC) + (size_t)chunk * 512 + k * 256 + w * 64) * 14);
        const float4* sv = (const float4*)&sout[k][w][0];
        ob[lane]       = sv[lane];
        ob[64 + lane]  = sv[64 + lane];
        ob[128 + lane] = sv[128 + lane];
        if (lane < 32) ob[192 + lane] = sv[192 + lane];
    }
}

extern "C" void kernel_launch(void* const* d_in, const int* in_sizes, int n_in,
                              void* d_out, int out_size, void* d_ws, size_t ws_size,
                              hipStream_t stream) {
    const float* gt = (const float*)d_in[3];
    const float* p3 = (const float*)d_in[4];
    const float* p4 = (const float*)d_in[5];
    const float* p5 = (const float*)d_in[6];
    float* out = (float*)d_out;

    dim3 grid(16 * CHUNKS);   // 672 blocks, each: one batch, 512 locations
    dim3 block(256);
    hipLaunchKernelGGL(fcos_assign, grid, block, 0, stream,
                       gt, p3, p4, p5, out);
}

// Round 7
// 10.328 us; speedup vs baseline: 1.2322x; 1.2322x over previous
//
#include <hip/hip_runtime.h>
#include <math.h>

#define NLOC 21504
#define N3 16384
#define N4 4096
#define N5 1024
#define CHUNKS 84   // 84 chunks of 256 locations per batch
// p3: chunks 0..63  (2 rows x 128 cols), wave = 1 row x 64 cols
// p4: chunks 64..79 (4 rows x 64 cols),  wave = 1 row x 64 cols
// p5: chunks 80..83 (8 rows x 32 cols),  wave = 2 rows x 32 cols

typedef float vfloat4 __attribute__((ext_vector_type(4)));

__global__ __launch_bounds__(256) void fcos_assign(
    const float* __restrict__ gt,      // (16, 64, 5)
    const float* __restrict__ pred3,   // (16, 16384, 4)
    const float* __restrict__ pred4,   // (16, 4096, 4)
    const float* __restrict__ pred5,   // (16, 1024, 4)
    float* __restrict__ out)           // (16, 21504, 14)
{
    // Wave-private candidate lists and output staging: NO __syncthreads anywhere.
    __shared__ float scand[4][64][8];   // 8 KiB  [x0,y0,x1,y1,cls,q,-,-]
    __shared__ float sout[4][896];      // 14 KiB (64 locations x 14 ch per wave)

    const int tid   = threadIdx.x;
    const int lane  = tid & 63;
    const int w     = tid >> 6;
    const int b     = blockIdx.x / CHUNKS;
    const int chunk = blockIdx.x % CHUNKS;

    // ---- issue gt loads FIRST: longest-latency item on the pre-ballot path ----
    const float* g = gt + (size_t)b * 320 + lane * 5;
    const float bx0 = g[0], by0 = g[1], bx1 = g[2], by1 = g[3], bcl = g[4];

    // ---- per-thread location, computed arithmetically (bit-exact vs _grid:
    //      (col+0.5)*2^k is exact in f32) + wave-uniform level/window params ----
    const int i = chunk * 256 + tid;     // global location index in [0, 21504)
    float cx, cy, stride, lower, upper;
    float cx_min, cx_max, cy_min, cy_max;   // wave's location window
    const float* pred;
    if (i < N3) {
        const int row = chunk * 2 + (w >> 1);
        const int col = (w & 1) * 64 + lane;
        cx = (col + 0.5f) * 8.0f;  cy = (row + 0.5f) * 8.0f;
        stride = 8.0f; lower = 0.0f; upper = 64.0f;
        cy_min = cy_max = cy;                       // 1 row per wave
        cx_min = ((w & 1) * 64 + 0.5f) * 8.0f;
        cx_max = ((w & 1) * 64 + 63.5f) * 8.0f;
        pred = pred3 + ((size_t)b * N3 + i) * 4;
    } else if (i < N3 + N4) {
        const int il  = i - N3;
        const int row = il >> 6;                    // = (chunk-64)*4 + w
        const int col = lane;
        cx = (col + 0.5f) * 16.0f;  cy = (row + 0.5f) * 16.0f;
        stride = 16.0f; lower = 64.0f; upper = 128.0f;
        cy_min = cy_max = cy;                       // 1 row per wave
        cx_min = 8.0f;  cx_max = 1016.0f;           // full width
        pred = pred4 + ((size_t)b * N4 + il) * 4;
    } else {
        const int il  = i - N3 - N4;
        const int row = il >> 5;                    // wave covers rows r0, r0+1
        const int col = lane & 31;
        cx = (col + 0.5f) * 32.0f;  cy = (row + 0.5f) * 32.0f;
        stride = 32.0f; lower = 128.0f; upper = INFINITY;
        const int r0 = (il - lane) >> 5;            // first row of this wave
        cy_min = (r0 + 0.5f) * 32.0f;  cy_max = (r0 + 1.5f) * 32.0f;
        cx_min = 16.0f;  cx_max = 1008.0f;          // full width
        pred = pred5 + ((size_t)b * N5 + il) * 4;
    }

    // ---- prefetch prediction (latency hides under filter + match loop) ----
    const float4 p = *(const float4*)pred;

    // ---- per-wave candidate filter: lane <-> box, ballot-compact ----
    // Necessary conditions only (with 0.25px margin >> any f32 rounding of the
    // reference's direct per-location tests), so no matchable box is dropped.
    // Order-preserving compaction keeps jnp.argmax first-max-wins semantics.
    const float eps = 0.25f;
    const float ylo = fmaxf(by0, by1 - upper), yhi = fminf(by1, by0 + upper);
    const float xlo = fmaxf(bx0, bx1 - upper), xhi = fminf(bx1, bx0 + upper);
    const bool keep = (ylo < cy_max + eps) && (yhi > cy_min - eps)
                   && (xlo < cx_max + eps) && (xhi > cx_min - eps)
                   && (fmaxf(bx1 - bx0, by1 - by0) > lower - eps);
    const unsigned long long mball = __ballot(keep);
    const int cnt = (int)__popcll(mball);
    if (keep) {
        const int pos = (int)__popcll(mball & ((1ull << lane) - 1ull));
        scand[w][pos][0] = bx0; scand[w][pos][1] = by0;
        scand[w][pos][2] = bx1; scand[w][pos][3] = by1;
        scand[w][pos][4] = bcl;
        // Exactly match JAX: q = 1e8 - (x1-x0)*(y1-y0), no FMA contraction.
        scand[w][pos][5] = __fsub_rn(1.0e8f,
                            __fmul_rn(__fsub_rn(bx1, bx0), __fsub_rn(by1, by0)));
    }
    __builtin_amdgcn_wave_barrier();   // wave-synchronous LDS: pin write->read order

    // ---- match loop over candidates (first-max-wins == jnp.argmax) ----
    float best = 0.0f;
    int   bi   = -1;
    for (int j = 0; j < cnt; ++j) {
        const float4 bx = *(const float4*)&scand[w][j][0];  // broadcast ds_read_b128
        const float  q  = scand[w][j][5];
        const float dl = cx - bx.x;
        const float dt = cy - bx.y;
        const float dr = bx.z - cx;
        const float db = bx.w - cy;
        const float mn = fminf(fminf(dl, dt), fminf(dr, db));
        const float mx = fmaxf(fmaxf(dl, dt), fmaxf(dr, db));
        const bool upd = (mn > 0.0f) && (mx > lower) && (mx < upper) && (q > best);
        best = upd ? q : best;
        bi   = upd ? j : bi;
    }

    float m0, m1, m2, m3, m4;
    if (bi < 0) {
        m0 = m1 = m2 = m3 = m4 = -1.0f;
    } else {
        const float4 bb = *(const float4*)&scand[w][bi][0];
        m0 = bb.x; m1 = bb.y; m2 = bb.z; m3 = bb.w;
        m4 = scand[w][bi][4];
    }

    // ---- targets + centerness ----
    const bool bg = (m4 == -1.0f);
    float t0, t1, t2, t3, ctr;
    if (bg) {
        t0 = t1 = t2 = t3 = -1.0f;
        ctr = -1.0f;
    } else {
        t0 = (cx - m0) / stride;   // exact: stride is a power of two
        t1 = (cy - m1) / stride;
        t2 = (m2 - cx) / stride;
        t3 = (m3 - cy) / stride;
        const float num = fminf(t0, t2) * fminf(t1, t3);
        const float den = fmaxf(t0, t2) * fmaxf(t1, t3);
        ctr = sqrtf(num / den);
    }

    // ---- decode predictions ----
    const float d0 = cx - fmaxf(p.x, 0.0f) * stride;
    const float d1 = cy - fmaxf(p.y, 0.0f) * stride;
    const float d2 = cx + fmaxf(p.z, 0.0f) * stride;
    const float d3 = cy + fmaxf(p.w, 0.0f) * stride;

    // ---- wave-private staging, then coalesced nontemporal float4 stores ----
    float2* so2 = (float2*)&sout[w][lane * 14];
    so2[0] = make_float2(d0, d1);
    so2[1] = make_float2(d2, d3);
    so2[2] = make_float2(m0, m1);
    so2[3] = make_float2(m2, m3);
    so2[4] = make_float2(m4, t0);
    so2[5] = make_float2(t1, t2);
    so2[6] = make_float2(t3, ctr);
    __builtin_amdgcn_wave_barrier();

    // 64 locations x 14 ch = 896 floats = 224 float4 per wave, contiguous.
    // Full-line streaming writes: nontemporal (no L2 allocation).
    vfloat4* ob = (vfloat4*)(out + (((size_t)b * NLOC) + (size_t)chunk * 256 + w * 64) * 14);
    const vfloat4* sv = (const vfloat4*)&sout[w][0];
    __builtin_nontemporal_store(sv[lane],        &ob[lane]);
    __builtin_nontemporal_store(sv[64 + lane],   &ob[64 + lane]);
    __builtin_nontemporal_store(sv[128 + lane],  &ob[128 + lane]);
    if (lane < 32)
        __builtin_nontemporal_store(sv[192 + lane], &ob[192 + lane]);
}

extern "C" void kernel_launch(void* const* d_in, const int* in_sizes, int n_in,
                              void* d_out, int out_size, void* d_ws, size_t ws_size,
                              hipStream_t stream) {
    const float* gt = (const float*)d_in[3];
    const float* p3 = (const float*)d_in[4];
    const float* p4 = (const float*)d_in[5];
    const float* p5 = (const float*)d_in[6];
    float* out = (float*)d_out;

    dim3 grid(16 * CHUNKS);   // 1344 blocks, each: one batch, 256 locations
    dim3 block(256);
    hipLaunchKernelGGL(fcos_assign, grid, block, 0, stream,
                       gt, p3, p4, p5, out);
}